// Round 1
// baseline (500.630 us; speedup 1.0000x reference)
//
#include <hip/hip_runtime.h>

#define NN 512
#define MM 512
#define INFV 1e8f

// One block per batch element. Thread t owns DP row i = t+1.
// Anti-diagonal wavefront with 3 rotating diagonal buffers in LDS.
// R[i,j] = D[i-1,j-1] + softmin(R[i-1,j-1], R[i-1,j], R[i,j-1]), gamma=1.
__global__ __launch_bounds__(512, 1) void sdtw_kernel(const float* __restrict__ D,
                                                      float* __restrict__ out) {
    const int b = blockIdx.x;
    const int tid = threadIdx.x;  // 0..511
    const int i = tid + 1;        // DP row 1..512

    __shared__ float buf[3][NN + 1];

    // Diagonal d=0: R[0,0]=0, rest out-of-matrix (INF).
    // Diagonal d=1: R[1,0]=R[0,1]=INF.
    buf[0][tid] = INFV;
    buf[1][tid] = INFV;
    if (tid == 0) {
        buf[0][0] = 0.0f;     // R[0,0]
        buf[0][NN] = INFV;
        buf[1][NN] = INFV;
    }
    __syncthreads();

    const float* __restrict__ Drow = D + (size_t)b * NN * MM + (size_t)(i - 1) * MM;
    float* __restrict__ outrow = out + (size_t)b * NN * MM + (size_t)(i - 1) * MM;

    int dm2 = 0, dm1 = 1, cur = 2;

    for (int d = 2; d <= NN + MM; ++d) {
        const int j = d - i;
        const bool valid = (j >= 1) && (j <= MM);
        float val = INFV;
        if (valid) {
            const float a = buf[dm2][i - 1];  // R[i-1, j-1]
            const float bb = buf[dm1][i - 1]; // R[i-1, j]
            const float c = buf[dm1][i];      // R[i,   j-1]
            const float m = fminf(fminf(a, bb), c);
            const float s = __expf(m - a) + __expf(m - bb) + __expf(m - c);
            val = Drow[j - 1] + (m - __logf(s));
            outrow[j - 1] = val;
        }
        // Writes target buf[cur], which nobody reads this iteration -> one
        // barrier per diagonal is sufficient (separates this iter's writes
        // from next iter's reads AND this iter's reads from next iter's
        // writes into the recycled buffer).
        buf[cur][i] = val;                 // invalid rows record INF (out of matrix)
        if (tid == 0) buf[cur][0] = INFV;  // boundary R[0, d] = INF for d >= 1
        __syncthreads();
        const int t = dm2; dm2 = dm1; dm1 = cur; cur = t;
    }
}

extern "C" void kernel_launch(void* const* d_in, const int* in_sizes, int n_in,
                              void* d_out, int out_size, void* d_ws, size_t ws_size,
                              hipStream_t stream) {
    const float* D = (const float*)d_in[0];
    float* out = (float*)d_out;
    const int B = in_sizes[0] / (NN * MM);
    sdtw_kernel<<<B, 512, 0, stream>>>(D, out);
}

// Round 5
// 458.141 us; speedup vs baseline: 1.0927x; 1.0927x over previous
//
#include <hip/hip_runtime.h>

#define NN 512
#define MM 512
#define INFV 1e8f

// One wave (64 lanes) per batch. Lane l owns rows 8l+1 .. 8l+8 (1-based DP rows).
// Column skew: at step t, lane l computes column j = t - l for its 8 rows.
// LOG-domain softmin (identical math to the R1 kernel that passed, absmax 2.0):
//   m = min(a,b,c); val = D + m - ln(e^{m-a} + e^{m-b} + e^{m-c})
// with a = R[i-1,j-1], b = R[i-1,j], c = R[i,j-1]; boundaries are the literal
// 1e8 constants, same as the reference. No scaling machinery needed: all
// quantities are plain R values (interior <= ~520, borders ~1e8, exp args <= 0).
//
// Cross-lane handoff via __shfl_up (wave-lockstep, no LDS, no barriers):
//   r_out = this lane's prevR[7] snapshot (R[8l+8, j] after step t computed col j)
//   up_r  = lane l-1's r_out from step t-1  = R[8l, j]   (vert-above for col j)
//   bp_r  = up_r from step t-1              = R[8l, j-1] (diag-above for col j)
// lane 0: up_r forced to INFV (R[0, j>=1] = INF); bp_r init 0.0 (R[0,0] = 0).
//
// D prefetch: parity double-buffer dA/dB; the buffer consumed at step t is
// refilled at step t for use at t+2 (~2 steps ≈ 500+ cycles of latency cover).
// All array indexing is compile-time constant (unrolled) -> registers.
__global__ __launch_bounds__(64, 1) void sdtw_wave(const float* __restrict__ D,
                                                   float* __restrict__ out) {
    const int b = blockIdx.x;
    const int lane = threadIdx.x;  // 0..63

    const size_t mat = (size_t)NN * MM;
    const float* __restrict__ Dl = D + (size_t)b * mat + (size_t)lane * 8 * MM;
    float* __restrict__ Ol = out + (size_t)b * mat + (size_t)lane * 8 * MM;

    float prevR[8];  // R[row, j-1] for this lane's 8 rows; R[row, 0] = INF
#pragma unroll
    for (int r = 0; r < 8; ++r) prevR[r] = INFV;

    float bp_r = (lane == 0) ? 0.0f : INFV;  // R[8l, j-1]; lane0 j=1 needs R[0,0]=0
    float r_out = INFV;                      // snapshot of prevR[7] (R[8l+8, j])

    // Initial fills: buffer consumed at step t holds D column (t - lane - 1),
    // clamped to [0, 511]. t=1 -> clamp(-lane)=0; t=2 -> clamp(1-lane).
    float dA[8], dB[8];
    {
        const int c1 = (lane == 0) ? 1 : 0;
#pragma unroll
        for (int r = 0; r < 8; ++r) dA[r] = Dl[r * MM];
#pragma unroll
        for (int r = 0; r < 8; ++r) dB[r] = Dl[r * MM + c1];
    }

    auto step = [&](int t, float* dc) {
        const int j = t - lane;
        const bool valid = (j >= 1) && (j <= MM);

        float up_r = __shfl_up(r_out, 1);  // lane l-1's R[8l, j]
        if (lane == 0) up_r = INFV;        // R[0, j>=1] = INF

        const float dAbove = bp_r;  // R[8l, j-1]
        const float vAbove = up_r;  // R[8l, j]
        bp_r = up_r;                // becomes diag-above for column j+1

        if (valid) {
            float diag = dAbove, vert = vAbove;
#pragma unroll
            for (int r = 0; r < 8; ++r) {
                const float a = diag, bb = vert, c = prevR[r];
                const float m = fminf(fminf(a, bb), c);
                const float s = __expf(m - a) + __expf(m - bb) + __expf(m - c);
                const float val = dc[r] + (m - __logf(s));
                diag = prevR[r];  // R[row, j-1] is next row's diag
                vert = val;       // R[row, j]   is next row's vert
                prevR[r] = val;
                Ol[r * MM + (j - 1)] = val;
            }
        }
        r_out = prevR[7];

        // refill this buffer for step t+2 (D column index j+1, clamped)
        const int jn = min(max(j + 1, 0), MM - 1);
#pragma unroll
        for (int r = 0; r < 8; ++r) dc[r] = Dl[r * MM + jn];
    };

    // steps t = 1 .. 575; odd t consumes dA, even t consumes dB
    for (int t = 1; t < 575; t += 2) {
        step(t, dA);
        step(t + 1, dB);
    }
    step(575, dA);
}

extern "C" void kernel_launch(void* const* d_in, const int* in_sizes, int n_in,
                              void* d_out, int out_size, void* d_ws, size_t ws_size,
                              hipStream_t stream) {
    const float* D = (const float*)d_in[0];
    float* out = (float*)d_out;
    const int B = in_sizes[0] / (NN * MM);
    sdtw_wave<<<B, 64, 0, stream>>>(D, out);
}